// Round 7
// baseline (1600.955 us; speedup 1.0000x reference)
//
#include <hip/hip_runtime.h>

#define NNODES 20000
#define NEDGES 320000
#define NB 16
#define FIN 256
#define NP 5
#define NA 5

// ===========================================================================
// CSR build: counting-sort edges by dst (per batch), once per launch.
// ===========================================================================

// count in-edges AND weighted degree per dst node, interleaved {sumw, cnt}
// (same cache line for both atomics -> ~1 line touch per edge)
__global__ __launch_bounds__(256) void count_kernel(const int* __restrict__ ei,
                                                    const float* __restrict__ ew,
                                                    float* __restrict__ cd) {
  int b = blockIdx.y;
  int e = blockIdx.x * 256 + threadIdx.x;  // grid.x = NEDGES/256 exact
  int dst = ei[b * 2 * NEDGES + NEDGES + e];
  float w = ew[b * NEDGES + e];
  long long o = ((long long)b * NNODES + dst) * 2;
  atomicAdd(&cd[o], w);
  atomicAdd(&cd[o + 1], 1.0f);  // counts <= few hundred: exact in fp32
}

// per-batch exclusive scan of cd[.,1] -> rowptr (global offsets, +b*NEDGES)
__global__ __launch_bounds__(1024) void scan_kernel(const float* __restrict__ cd,
                                                    int* __restrict__ rowptr) {
  int b = blockIdx.x;
  int tid = threadIdx.x;
  int lane = tid & 63, wid = tid >> 6;
  __shared__ int wsum[16];
  int carry = 0;
  for (int base = 0; base <= NNODES; base += 1024) {
    int i = base + tid;
    int v = (i < NNODES) ? (int)cd[((long long)b * NNODES + i) * 2 + 1] : 0;
    int x = v;
#pragma unroll
    for (int off = 1; off < 64; off <<= 1) {
      int y = __shfl_up(x, off);
      if (lane >= off) x += y;
    }
    if (lane == 63) wsum[wid] = x;
    __syncthreads();
    if (wid == 0) {
      int s = (lane < 16) ? wsum[lane] : 0;
#pragma unroll
      for (int off = 1; off < 16; off <<= 1) {
        int y = __shfl_up(s, off);
        if (lane >= off) s += y;
      }
      if (lane < 16) wsum[lane] = s;  // inclusive wave-sum scan
    }
    __syncthreads();
    int wpre = (wid == 0) ? 0 : wsum[wid - 1];
    int excl = x + wpre - v;  // exclusive prefix within chunk
    if (i <= NNODES) rowptr[b * (NNODES + 1) + i] = b * NEDGES + carry + excl;
    carry += wsum[15];
    __syncthreads();  // protect wsum before next iteration overwrites
  }
}

// dis = rsqrt(deg), inv = 1/deg, deg = 1 + sumw   (elementwise from cd)
__global__ __launch_bounds__(256) void deg_final_kernel(
    const float* __restrict__ cd, float* __restrict__ dis,
    float* __restrict__ inv) {
  long long i = (long long)blockIdx.x * 256 + threadIdx.x;
  if (i < (long long)NB * NNODES) {
    float d = cd[2 * i] + 1.0f;
    dis[i] = rsqrtf(d);
    inv[i] = 1.0f / d;
  }
}

// scatter edges into CSR slots: csr[pos] = {src, bits(w*dis[src])}
// (dis fold done here -> no separate csrw_transform pass)
__global__ __launch_bounds__(256) void scatter_kernel(
    const int* __restrict__ ei, const float* __restrict__ ew,
    const float* __restrict__ dis, const int* __restrict__ rowptr,
    int* __restrict__ cur, int2* __restrict__ csr) {
  int b = blockIdx.y;
  int e = blockIdx.x * 256 + threadIdx.x;
  const int* eib = ei + b * 2 * NEDGES;
  int src = eib[e];
  int dst = eib[NEDGES + e];
  float w = ew[b * NEDGES + e] * dis[b * NNODES + src];
  int pos = rowptr[b * (NNODES + 1) + dst] + atomicAdd(&cur[b * NNODES + dst], 1);
  csr[pos] = make_int2(src, __float_as_int(w));
}

// ===========================================================================
// per-layer gather + fused combine:
// out[n][j] = maybe_tanh( dis[n]*sum_k csr_w[k]*xw[src_k][j]
//                         + xw[n][j]*inv[n] + bias[j] )
// F threads per node; unroll 4 for memory-level parallelism
// ===========================================================================
template <int F, bool TANH>
__global__ __launch_bounds__(256) void gather_kernel(
    const int* __restrict__ rowptr, const int2* __restrict__ csr,
    const float* __restrict__ dis, const float* __restrict__ inv,
    const float* __restrict__ xw, const float* __restrict__ bias,
    float* __restrict__ out) {
  constexpr int NPB = 256 / F;
  int b = blockIdx.y;
  int n = blockIdx.x * NPB + threadIdx.x / F;  // grid.x exact divisor
  int j = threadIdx.x & (F - 1);
  long long bn = (long long)b * NNODES + n;
  int start = rowptr[b * (NNODES + 1) + n];
  int end = rowptr[b * (NNODES + 1) + n + 1];
  const float* xwb = xw + (long long)b * NNODES * F;
  float acc0 = 0.0f, acc1 = 0.0f, acc2 = 0.0f, acc3 = 0.0f;
  int k = start;
  for (; k + 4 <= end; k += 4) {
    int2 p0 = csr[k];
    int2 p1 = csr[k + 1];
    int2 p2 = csr[k + 2];
    int2 p3 = csr[k + 3];
    acc0 += __int_as_float(p0.y) * xwb[p0.x * F + j];
    acc1 += __int_as_float(p1.y) * xwb[p1.x * F + j];
    acc2 += __int_as_float(p2.y) * xwb[p2.x * F + j];
    acc3 += __int_as_float(p3.y) * xwb[p3.x * F + j];
  }
  for (; k < end; ++k) {
    int2 p = csr[k];
    acc0 += __int_as_float(p.y) * xwb[p.x * F + j];
  }
  float self = xwb[n * F + j];
  float r = dis[bn] * ((acc0 + acc1) + (acc2 + acc3)) + self * inv[bn] + bias[j];
  out[bn * F + j] = TANH ? tanhf(r) : r;
}

// ===========================================================================
// dense kernels (unchanged)
// ===========================================================================
__device__ __forceinline__ float wave_reduce16(const float p[16], int lane) {
  float v8[8];
  {
    const bool hi = lane & 1;
#pragma unroll
    for (int q = 0; q < 8; ++q) {
      float keep = hi ? p[2 * q + 1] : p[2 * q];
      float give = hi ? p[2 * q] : p[2 * q + 1];
      v8[q] = keep + __shfl_xor(give, 1);
    }
  }
  float v4[4];
  {
    const bool hi = (lane >> 1) & 1;
#pragma unroll
    for (int q = 0; q < 4; ++q) {
      float keep = hi ? v8[2 * q + 1] : v8[2 * q];
      float give = hi ? v8[2 * q] : v8[2 * q + 1];
      v4[q] = keep + __shfl_xor(give, 2);
    }
  }
  float v2[2];
  {
    const bool hi = (lane >> 2) & 1;
#pragma unroll
    for (int q = 0; q < 2; ++q) {
      float keep = hi ? v4[2 * q + 1] : v4[2 * q];
      float give = hi ? v4[2 * q] : v4[2 * q + 1];
      v2[q] = keep + __shfl_xor(give, 4);
    }
  }
  float v1;
  {
    const bool hi = (lane >> 3) & 1;
    float keep = hi ? v2[1] : v2[0];
    float give = hi ? v2[0] : v2[1];
    v1 = keep + __shfl_xor(give, 8);
  }
  v1 += __shfl_xor(v1, 16);
  v1 += __shfl_xor(v1, 32);
  return v1;
}

__global__ __launch_bounds__(256) void mm1_kernel(
    const float* __restrict__ x, const float* __restrict__ W1,
    float* __restrict__ xw) {
  const int lane = threadIdx.x & 63;
  const int wib = threadIdx.x >> 6;
  const int wave = blockIdx.x * 4 + wib;
  const int nwaves = gridDim.x * 4;

  float wreg[64];
  {
    const float4* W4 = (const float4*)(W1 + lane * 64);
#pragma unroll
    for (int q = 0; q < 16; ++q) {
      float4 v = W4[q];
      wreg[q * 4 + 0] = v.x;
      wreg[q * 4 + 1] = v.y;
      wreg[q * 4 + 2] = v.z;
      wreg[q * 4 + 3] = v.w;
    }
  }
  const int nrows = NB * NNODES;
  for (int row = wave; row < nrows; row += nwaves) {
    float4 xv = ((const float4*)x)[(long long)row * 64 + lane];
    float p[16];
#pragma unroll
    for (int j = 0; j < 16; ++j) {
      p[j] = xv.x * wreg[j] + xv.y * wreg[16 + j] + xv.z * wreg[32 + j] +
             xv.w * wreg[48 + j];
    }
    float v = wave_reduce16(p, lane);
    if (lane < 16) xw[(long long)row * 16 + lane] = v;
  }
}

template <int FOUT>
__global__ __launch_bounds__(256) void mm_small_kernel(
    const float* __restrict__ h, const float* __restrict__ W,
    float* __restrict__ out) {
  __shared__ float Ws[16 * FOUT];
  for (int t = threadIdx.x; t < 16 * FOUT; t += 256) Ws[t] = W[t];
  __syncthreads();
  int idx = blockIdx.x * 256 + threadIdx.x;
  if (idx >= NB * NNODES * FOUT) return;
  int row = idx / FOUT;
  int j = idx & (FOUT - 1);
  const float4* hr = (const float4*)(h + (long long)row * 16);
  float hv[16];
#pragma unroll
  for (int q = 0; q < 4; ++q) {
    float4 v = hr[q];
    hv[q * 4 + 0] = v.x;
    hv[q * 4 + 1] = v.y;
    hv[q * 4 + 2] = v.z;
    hv[q * 4 + 3] = v.w;
  }
  float acc = 0.0f;
#pragma unroll
  for (int k = 0; k < 16; ++k) acc += hv[k] * Ws[k * FOUT + j];
  out[idx] = acc;
}

__global__ __launch_bounds__(256) void fc_kernel(
    const float* __restrict__ emb, const int* __restrict__ pos,
    const float* __restrict__ fcW1, const float* __restrict__ fcb1,
    const float* __restrict__ fcW2, const float* __restrict__ fcb2,
    const float* __restrict__ fcW3, const float* __restrict__ fcb3,
    float* __restrict__ out) {
  int b = blockIdx.x;
  int tid = threadIdx.x;
  __shared__ float flat[160];
  __shared__ float hb[128];
  if (tid < 160) {
    int p = tid / 32, j = tid & 31;
    int pv = pos[b * NP + p];
    float v;
    if (pv == -1) {
      v = -3.0f;  // -DEPTH
    } else {
      int node = pv < 0 ? 0 : (pv > NNODES - 1 ? NNODES - 1 : pv);
      v = emb[((long long)b * NNODES + node) * 32 + j];
    }
    flat[tid] = v;
  }
  __syncthreads();
  float acc1 = 0.0f;
  if (tid < 128) {
    acc1 = fcb1[tid];
#pragma unroll 8
    for (int k = 0; k < 160; ++k) acc1 += flat[k] * fcW1[k * 128 + tid];
    acc1 = tanhf(acc1);
  }
  __syncthreads();
  if (tid < 128) hb[tid] = acc1;
  __syncthreads();
  float acc2 = 0.0f;
  if (tid < 128) {
    acc2 = fcb2[tid];
#pragma unroll 8
    for (int k = 0; k < 128; ++k) acc2 += hb[k] * fcW2[k * 128 + tid];
    acc2 = tanhf(acc2);
  }
  __syncthreads();
  if (tid < 128) flat[tid] = acc2;
  __syncthreads();
  if (tid < NA) {
    float acc = fcb3[tid];
#pragma unroll 8
    for (int k = 0; k < 128; ++k) acc += flat[k] * fcW3[k * NA + tid];
    out[b * NA + tid] = acc;
  }
}

// ===========================================================================
extern "C" void kernel_launch(void* const* d_in, const int* in_sizes, int n_in,
                              void* d_out, int out_size, void* d_ws,
                              size_t ws_size, hipStream_t stream) {
  const float* x = (const float*)d_in[0];
  const int* ei = (const int*)d_in[1];
  const float* ew = (const float*)d_in[2];
  const int* pos = (const int*)d_in[3];
  const float* W1 = (const float*)d_in[4];
  const float* b1 = (const float*)d_in[5];
  const float* W2 = (const float*)d_in[6];
  const float* b2 = (const float*)d_in[7];
  const float* W3 = (const float*)d_in[8];
  const float* b3 = (const float*)d_in[9];
  const float* fcW1 = (const float*)d_in[10];
  const float* fcb1 = (const float*)d_in[11];
  const float* fcW2 = (const float*)d_in[12];
  const float* fcb2 = (const float*)d_in[13];
  const float* fcW3 = (const float*)d_in[14];
  const float* fcb3 = (const float*)d_in[15];
  float* out = (float*)d_out;

  const long long BN = (long long)NB * NNODES;  // 320000
  // workspace layout (prefix before csr is even #ints -> csr 8B aligned)
  float* cd = (float*)d_ws;                    // 2*BN  {sumw, cnt}
  int* rowptr = (int*)(cd + 2 * BN);           // NB*(NNODES+1) = 320016
  int* cur = rowptr + NB * (NNODES + 1);       // BN
  float* dis = (float*)(cur + BN);             // BN
  float* inv = dis + BN;                       // BN
  int2* csr = (int2*)(inv + BN);               // NB*NEDGES int2 = 40.96 MB
  float* bufA = (float*)(csr + (long long)NB * NEDGES);  // BN*32
  float* bufB = bufA + BN * 32;                // BN*32
  // total ~130 MB

  const dim3 egrid(NEDGES / 256, NB);  // 1250 x 16, exact

  // ---- CSR build (once; reused by all 3 layers) ----
  hipMemsetAsync(cd, 0, 2 * BN * sizeof(float), stream);
  hipMemsetAsync(cur, 0, BN * sizeof(int), stream);
  count_kernel<<<egrid, 256, 0, stream>>>(ei, ew, cd);
  scan_kernel<<<NB, 1024, 0, stream>>>(cd, rowptr);
  deg_final_kernel<<<(int)((BN + 255) / 256), 256, 0, stream>>>(cd, dis, inv);
  scatter_kernel<<<egrid, 256, 0, stream>>>(ei, ew, dis, rowptr, cur, csr);

  // ---- layer 1: x @ W1 -> 16, gather+combine+tanh ----
  mm1_kernel<<<4096, 256, 0, stream>>>(x, W1, bufA);
  gather_kernel<16, true><<<dim3(NNODES / 16, NB), 256, 0, stream>>>(
      rowptr, csr, dis, inv, bufA, b1, bufB);

  // ---- layer 2 ----
  mm_small_kernel<16><<<(int)(BN * 16 / 256), 256, 0, stream>>>(bufB, W2, bufA);
  gather_kernel<16, true><<<dim3(NNODES / 16, NB), 256, 0, stream>>>(
      rowptr, csr, dis, inv, bufA, b2, bufB);

  // ---- layer 3 ----
  mm_small_kernel<32><<<(int)(BN * 32 / 256), 256, 0, stream>>>(bufB, W3, bufA);
  gather_kernel<32, false><<<dim3(NNODES / 8, NB), 256, 0, stream>>>(
      rowptr, csr, dis, inv, bufA, b3, bufB);

  // ---- gather + MLP head ----
  fc_kernel<<<NB, 256, 0, stream>>>(bufB, pos, fcW1, fcb1, fcW2, fcb2, fcW3,
                                    fcb3, out);
}

// Round 8
// 1509.749 us; speedup vs baseline: 1.0604x; 1.0604x over previous
//
#include <hip/hip_runtime.h>

#define NNODES 20000
#define NEDGES 320000
#define NB 16
#define FIN 256
#define NP 5
#define NA 5
#define NRANGE 16                 // dst-range blocks per batch
#define RSPAN (NNODES / NRANGE)   // 1250 nodes per range

// ===========================================================================
// CSR build, pass 1: range-partitioned histogram — NO global atomics.
// Block (r,b) owns dst range [r*RSPAN, (r+1)*RSPAN); streams all dsts of
// batch b (int4), accumulates {cnt,sumw} in LDS, flushes with plain stores.
// ===========================================================================
__global__ __launch_bounds__(256) void hist_kernel(const int* __restrict__ ei,
                                                   const float* __restrict__ ew,
                                                   int* __restrict__ cnt,
                                                   float* __restrict__ sumw) {
  int r = blockIdx.x;
  int b = blockIdx.y;
  const int lo = r * RSPAN;
  __shared__ int lcnt[RSPAN];
  __shared__ float lsum[RSPAN];
  for (int i = threadIdx.x; i < RSPAN; i += 256) {
    lcnt[i] = 0;
    lsum[i] = 0.0f;
  }
  __syncthreads();
  const int4* dst4 = (const int4*)(ei + b * 2 * NEDGES + NEDGES);
  const float* ewb = ew + b * NEDGES;
  for (int q = threadIdx.x; q < NEDGES / 4; q += 256) {
    int4 d = dst4[q];
    int e0 = q * 4;
    int c0 = d.x - lo, c1 = d.y - lo, c2 = d.z - lo, c3 = d.w - lo;
    if ((unsigned)c0 < (unsigned)RSPAN) {
      atomicAdd(&lcnt[c0], 1);
      atomicAdd(&lsum[c0], ewb[e0]);
    }
    if ((unsigned)c1 < (unsigned)RSPAN) {
      atomicAdd(&lcnt[c1], 1);
      atomicAdd(&lsum[c1], ewb[e0 + 1]);
    }
    if ((unsigned)c2 < (unsigned)RSPAN) {
      atomicAdd(&lcnt[c2], 1);
      atomicAdd(&lsum[c2], ewb[e0 + 2]);
    }
    if ((unsigned)c3 < (unsigned)RSPAN) {
      atomicAdd(&lcnt[c3], 1);
      atomicAdd(&lsum[c3], ewb[e0 + 3]);
    }
  }
  __syncthreads();
  for (int i = threadIdx.x; i < RSPAN; i += 256) {
    cnt[b * NNODES + lo + i] = lcnt[i];
    sumw[b * NNODES + lo + i] = lsum[i];
  }
}

// per-batch exclusive scan of cnt -> rowptr (global offsets, +b*NEDGES)
__global__ __launch_bounds__(1024) void scan_kernel(const int* __restrict__ cnt,
                                                    int* __restrict__ rowptr) {
  int b = blockIdx.x;
  int tid = threadIdx.x;
  int lane = tid & 63, wid = tid >> 6;
  __shared__ int wsum[16];
  int carry = 0;
  for (int base = 0; base <= NNODES; base += 1024) {
    int i = base + tid;
    int v = (i < NNODES) ? cnt[b * NNODES + i] : 0;
    int x = v;
#pragma unroll
    for (int off = 1; off < 64; off <<= 1) {
      int y = __shfl_up(x, off);
      if (lane >= off) x += y;
    }
    if (lane == 63) wsum[wid] = x;
    __syncthreads();
    if (wid == 0) {
      int s = (lane < 16) ? wsum[lane] : 0;
#pragma unroll
      for (int off = 1; off < 16; off <<= 1) {
        int y = __shfl_up(s, off);
        if (lane >= off) s += y;
      }
      if (lane < 16) wsum[lane] = s;  // inclusive wave-sum scan
    }
    __syncthreads();
    int wpre = (wid == 0) ? 0 : wsum[wid - 1];
    int excl = x + wpre - v;  // exclusive prefix within chunk
    if (i <= NNODES) rowptr[b * (NNODES + 1) + i] = b * NEDGES + carry + excl;
    carry += wsum[15];
    __syncthreads();  // protect wsum before next iteration overwrites
  }
}

// dis = rsqrt(1+sumw), inv = 1/(1+sumw)   (elementwise)
__global__ __launch_bounds__(256) void deg_final_kernel(
    const float* __restrict__ sumw, float* __restrict__ dis,
    float* __restrict__ inv) {
  long long i = (long long)blockIdx.x * 256 + threadIdx.x;
  if (i < (long long)NB * NNODES) {
    float d = sumw[i] + 1.0f;
    dis[i] = rsqrtf(d);
    inv[i] = 1.0f / d;
  }
}

// scatter edges into CSR slots: csr[pos] = {src, bits(w*dis[src])}
__global__ __launch_bounds__(256) void scatter_kernel(
    const int* __restrict__ ei, const float* __restrict__ ew,
    const float* __restrict__ dis, const int* __restrict__ rowptr,
    int* __restrict__ cur, int2* __restrict__ csr) {
  int b = blockIdx.y;
  int e = blockIdx.x * 256 + threadIdx.x;
  const int* eib = ei + b * 2 * NEDGES;
  int src = eib[e];
  int dst = eib[NEDGES + e];
  float w = ew[b * NEDGES + e] * dis[b * NNODES + src];
  int pos = rowptr[b * (NNODES + 1) + dst] + atomicAdd(&cur[b * NNODES + dst], 1);
  csr[pos] = make_int2(src, __float_as_int(w));
}

// ===========================================================================
// per-layer gather + fused combine:
// out[n][j] = maybe_tanh( dis[n]*sum_k csr_w[k]*xw[src_k][j]
//                         + xw[n][j]*inv[n] + bias[j] )
// F threads per node; unroll 4 for memory-level parallelism
// ===========================================================================
template <int F, bool TANH>
__global__ __launch_bounds__(256) void gather_kernel(
    const int* __restrict__ rowptr, const int2* __restrict__ csr,
    const float* __restrict__ dis, const float* __restrict__ inv,
    const float* __restrict__ xw, const float* __restrict__ bias,
    float* __restrict__ out) {
  constexpr int NPB = 256 / F;
  int b = blockIdx.y;
  int n = blockIdx.x * NPB + threadIdx.x / F;  // grid.x exact divisor
  int j = threadIdx.x & (F - 1);
  long long bn = (long long)b * NNODES + n;
  int start = rowptr[b * (NNODES + 1) + n];
  int end = rowptr[b * (NNODES + 1) + n + 1];
  const float* xwb = xw + (long long)b * NNODES * F;
  float acc0 = 0.0f, acc1 = 0.0f, acc2 = 0.0f, acc3 = 0.0f;
  int k = start;
  for (; k + 4 <= end; k += 4) {
    int2 p0 = csr[k];
    int2 p1 = csr[k + 1];
    int2 p2 = csr[k + 2];
    int2 p3 = csr[k + 3];
    acc0 += __int_as_float(p0.y) * xwb[p0.x * F + j];
    acc1 += __int_as_float(p1.y) * xwb[p1.x * F + j];
    acc2 += __int_as_float(p2.y) * xwb[p2.x * F + j];
    acc3 += __int_as_float(p3.y) * xwb[p3.x * F + j];
  }
  for (; k < end; ++k) {
    int2 p = csr[k];
    acc0 += __int_as_float(p.y) * xwb[p.x * F + j];
  }
  float self = xwb[n * F + j];
  float r = dis[bn] * ((acc0 + acc1) + (acc2 + acc3)) + self * inv[bn] + bias[j];
  out[bn * F + j] = TANH ? tanhf(r) : r;
}

// ===========================================================================
// dense kernels (unchanged)
// ===========================================================================
__device__ __forceinline__ float wave_reduce16(const float p[16], int lane) {
  float v8[8];
  {
    const bool hi = lane & 1;
#pragma unroll
    for (int q = 0; q < 8; ++q) {
      float keep = hi ? p[2 * q + 1] : p[2 * q];
      float give = hi ? p[2 * q] : p[2 * q + 1];
      v8[q] = keep + __shfl_xor(give, 1);
    }
  }
  float v4[4];
  {
    const bool hi = (lane >> 1) & 1;
#pragma unroll
    for (int q = 0; q < 4; ++q) {
      float keep = hi ? v8[2 * q + 1] : v8[2 * q];
      float give = hi ? v8[2 * q] : v8[2 * q + 1];
      v4[q] = keep + __shfl_xor(give, 2);
    }
  }
  float v2[2];
  {
    const bool hi = (lane >> 2) & 1;
#pragma unroll
    for (int q = 0; q < 2; ++q) {
      float keep = hi ? v4[2 * q + 1] : v4[2 * q];
      float give = hi ? v4[2 * q] : v4[2 * q + 1];
      v2[q] = keep + __shfl_xor(give, 4);
    }
  }
  float v1;
  {
    const bool hi = (lane >> 3) & 1;
    float keep = hi ? v2[1] : v2[0];
    float give = hi ? v2[0] : v2[1];
    v1 = keep + __shfl_xor(give, 8);
  }
  v1 += __shfl_xor(v1, 16);
  v1 += __shfl_xor(v1, 32);
  return v1;
}

__global__ __launch_bounds__(256) void mm1_kernel(
    const float* __restrict__ x, const float* __restrict__ W1,
    float* __restrict__ xw) {
  const int lane = threadIdx.x & 63;
  const int wib = threadIdx.x >> 6;
  const int wave = blockIdx.x * 4 + wib;
  const int nwaves = gridDim.x * 4;

  float wreg[64];
  {
    const float4* W4 = (const float4*)(W1 + lane * 64);
#pragma unroll
    for (int q = 0; q < 16; ++q) {
      float4 v = W4[q];
      wreg[q * 4 + 0] = v.x;
      wreg[q * 4 + 1] = v.y;
      wreg[q * 4 + 2] = v.z;
      wreg[q * 4 + 3] = v.w;
    }
  }
  const int nrows = NB * NNODES;
  for (int row = wave; row < nrows; row += nwaves) {
    float4 xv = ((const float4*)x)[(long long)row * 64 + lane];
    float p[16];
#pragma unroll
    for (int j = 0; j < 16; ++j) {
      p[j] = xv.x * wreg[j] + xv.y * wreg[16 + j] + xv.z * wreg[32 + j] +
             xv.w * wreg[48 + j];
    }
    float v = wave_reduce16(p, lane);
    if (lane < 16) xw[(long long)row * 16 + lane] = v;
  }
}

template <int FOUT>
__global__ __launch_bounds__(256) void mm_small_kernel(
    const float* __restrict__ h, const float* __restrict__ W,
    float* __restrict__ out) {
  __shared__ float Ws[16 * FOUT];
  for (int t = threadIdx.x; t < 16 * FOUT; t += 256) Ws[t] = W[t];
  __syncthreads();
  int idx = blockIdx.x * 256 + threadIdx.x;
  if (idx >= NB * NNODES * FOUT) return;
  int row = idx / FOUT;
  int j = idx & (FOUT - 1);
  const float4* hr = (const float4*)(h + (long long)row * 16);
  float hv[16];
#pragma unroll
  for (int q = 0; q < 4; ++q) {
    float4 v = hr[q];
    hv[q * 4 + 0] = v.x;
    hv[q * 4 + 1] = v.y;
    hv[q * 4 + 2] = v.z;
    hv[q * 4 + 3] = v.w;
  }
  float acc = 0.0f;
#pragma unroll
  for (int k = 0; k < 16; ++k) acc += hv[k] * Ws[k * FOUT + j];
  out[idx] = acc;
}

__global__ __launch_bounds__(256) void fc_kernel(
    const float* __restrict__ emb, const int* __restrict__ pos,
    const float* __restrict__ fcW1, const float* __restrict__ fcb1,
    const float* __restrict__ fcW2, const float* __restrict__ fcb2,
    const float* __restrict__ fcW3, const float* __restrict__ fcb3,
    float* __restrict__ out) {
  int b = blockIdx.x;
  int tid = threadIdx.x;
  __shared__ float flat[160];
  __shared__ float hb[128];
  if (tid < 160) {
    int p = tid / 32, j = tid & 31;
    int pv = pos[b * NP + p];
    float v;
    if (pv == -1) {
      v = -3.0f;  // -DEPTH
    } else {
      int node = pv < 0 ? 0 : (pv > NNODES - 1 ? NNODES - 1 : pv);
      v = emb[((long long)b * NNODES + node) * 32 + j];
    }
    flat[tid] = v;
  }
  __syncthreads();
  float acc1 = 0.0f;
  if (tid < 128) {
    acc1 = fcb1[tid];
#pragma unroll 8
    for (int k = 0; k < 160; ++k) acc1 += flat[k] * fcW1[k * 128 + tid];
    acc1 = tanhf(acc1);
  }
  __syncthreads();
  if (tid < 128) hb[tid] = acc1;
  __syncthreads();
  float acc2 = 0.0f;
  if (tid < 128) {
    acc2 = fcb2[tid];
#pragma unroll 8
    for (int k = 0; k < 128; ++k) acc2 += hb[k] * fcW2[k * 128 + tid];
    acc2 = tanhf(acc2);
  }
  __syncthreads();
  if (tid < 128) flat[tid] = acc2;
  __syncthreads();
  if (tid < NA) {
    float acc = fcb3[tid];
#pragma unroll 8
    for (int k = 0; k < 128; ++k) acc += flat[k] * fcW3[k * NA + tid];
    out[b * NA + tid] = acc;
  }
}

// ===========================================================================
extern "C" void kernel_launch(void* const* d_in, const int* in_sizes, int n_in,
                              void* d_out, int out_size, void* d_ws,
                              size_t ws_size, hipStream_t stream) {
  const float* x = (const float*)d_in[0];
  const int* ei = (const int*)d_in[1];
  const float* ew = (const float*)d_in[2];
  const int* pos = (const int*)d_in[3];
  const float* W1 = (const float*)d_in[4];
  const float* b1 = (const float*)d_in[5];
  const float* W2 = (const float*)d_in[6];
  const float* b2 = (const float*)d_in[7];
  const float* W3 = (const float*)d_in[8];
  const float* b3 = (const float*)d_in[9];
  const float* fcW1 = (const float*)d_in[10];
  const float* fcb1 = (const float*)d_in[11];
  const float* fcW2 = (const float*)d_in[12];
  const float* fcb2 = (const float*)d_in[13];
  const float* fcW3 = (const float*)d_in[14];
  const float* fcb3 = (const float*)d_in[15];
  float* out = (float*)d_out;

  const long long BN = (long long)NB * NNODES;  // 320000
  // workspace layout (prefix before csr is even #ints -> csr 8B aligned)
  int* cnt = (int*)d_ws;                       // BN
  float* sumw = (float*)(cnt + BN);            // BN
  int* rowptr = (int*)(sumw + BN);             // NB*(NNODES+1) = 320016
  int* cur = rowptr + NB * (NNODES + 1);       // BN
  float* dis = (float*)(cur + BN);             // BN
  float* inv = dis + BN;                       // BN
  int2* csr = (int2*)(inv + BN);               // NB*NEDGES int2 = 40.96 MB
  float* bufA = (float*)(csr + (long long)NB * NEDGES);  // BN*32
  float* bufB = bufA + BN * 32;                // BN*32
  // total ~130 MB

  const dim3 egrid(NEDGES / 256, NB);  // 1250 x 16, exact

  // ---- CSR build (once; reused by all 3 layers) ----
  hist_kernel<<<dim3(NRANGE, NB), 256, 0, stream>>>(ei, ew, cnt, sumw);
  scan_kernel<<<NB, 1024, 0, stream>>>(cnt, rowptr);
  deg_final_kernel<<<(int)((BN + 255) / 256), 256, 0, stream>>>(sumw, dis, inv);
  hipMemsetAsync(cur, 0, BN * sizeof(int), stream);
  scatter_kernel<<<egrid, 256, 0, stream>>>(ei, ew, dis, rowptr, cur, csr);

  // ---- layer 1: x @ W1 -> 16, gather+combine+tanh ----
  mm1_kernel<<<4096, 256, 0, stream>>>(x, W1, bufA);
  gather_kernel<16, true><<<dim3(NNODES / 16, NB), 256, 0, stream>>>(
      rowptr, csr, dis, inv, bufA, b1, bufB);

  // ---- layer 2 ----
  mm_small_kernel<16><<<(int)(BN * 16 / 256), 256, 0, stream>>>(bufB, W2, bufA);
  gather_kernel<16, true><<<dim3(NNODES / 16, NB), 256, 0, stream>>>(
      rowptr, csr, dis, inv, bufA, b2, bufB);

  // ---- layer 3 ----
  mm_small_kernel<32><<<(int)(BN * 32 / 256), 256, 0, stream>>>(bufB, W3, bufA);
  gather_kernel<32, false><<<dim3(NNODES / 8, NB), 256, 0, stream>>>(
      rowptr, csr, dis, inv, bufA, b3, bufB);

  // ---- gather + MLP head ----
  fc_kernel<<<NB, 256, 0, stream>>>(bufB, pos, fcW1, fcb1, fcW2, fcb2, fcW3,
                                    fcb3, out);
}

// Round 9
// 1369.285 us; speedup vs baseline: 1.1692x; 1.1026x over previous
//
#include <hip/hip_runtime.h>

#define NNODES 20000
#define NEDGES 320000
#define NB 16
#define FIN 256
#define NP 5
#define NA 5

// ===========================================================================
// CSR build: counting-sort edges by dst (per batch), once per launch.
// count = plain int atomics (measured-cheap in round 6; rounds 7/8 regressed
// with fused-fp32 / LDS-histogram variants -> reverted).
// ===========================================================================
__global__ __launch_bounds__(256) void count_kernel(const int* __restrict__ ei,
                                                    int* __restrict__ cnt) {
  int b = blockIdx.y;
  int e = blockIdx.x * 256 + threadIdx.x;  // grid.x = NEDGES/256 exact
  int dst = ei[b * 2 * NEDGES + NEDGES + e];
  atomicAdd(&cnt[b * NNODES + dst], 1);
}

// per-batch exclusive scan of cnt -> rowptr (global offsets, +b*NEDGES)
__global__ __launch_bounds__(1024) void scan_kernel(const int* __restrict__ cnt,
                                                    int* __restrict__ rowptr) {
  int b = blockIdx.x;
  int tid = threadIdx.x;
  int lane = tid & 63, wid = tid >> 6;
  __shared__ int wsum[16];
  int carry = 0;
  for (int base = 0; base <= NNODES; base += 1024) {
    int i = base + tid;
    int v = (i < NNODES) ? cnt[b * NNODES + i] : 0;
    int x = v;
#pragma unroll
    for (int off = 1; off < 64; off <<= 1) {
      int y = __shfl_up(x, off);
      if (lane >= off) x += y;
    }
    if (lane == 63) wsum[wid] = x;
    __syncthreads();
    if (wid == 0) {
      int s = (lane < 16) ? wsum[lane] : 0;
#pragma unroll
      for (int off = 1; off < 16; off <<= 1) {
        int y = __shfl_up(s, off);
        if (lane >= off) s += y;
      }
      if (lane < 16) wsum[lane] = s;  // inclusive wave-sum scan
    }
    __syncthreads();
    int wpre = (wid == 0) ? 0 : wsum[wid - 1];
    int excl = x + wpre - v;  // exclusive prefix within chunk
    if (i <= NNODES) rowptr[b * (NNODES + 1) + i] = b * NEDGES + carry + excl;
    carry += wsum[15];
    __syncthreads();  // protect wsum before next iteration overwrites
  }
}

// scatter edges into CSR slots: csr[pos] = {src, bits(w)}  (raw w; dis[src]
// is applied in gather from the L2-resident per-batch dis table)
__global__ __launch_bounds__(256) void scatter_kernel(
    const int* __restrict__ ei, const float* __restrict__ ew,
    const int* __restrict__ rowptr, int* __restrict__ cur,
    int2* __restrict__ csr) {
  int b = blockIdx.y;
  int e = blockIdx.x * 256 + threadIdx.x;
  const int* eib = ei + b * 2 * NEDGES;
  int src = eib[e];
  int dst = eib[NEDGES + e];
  float w = ew[b * NEDGES + e];
  int pos = rowptr[b * (NNODES + 1) + dst] + atomicAdd(&cur[b * NNODES + dst], 1);
  csr[pos] = make_int2(src, __float_as_int(w));
}

// per-node walk of contiguous CSR range -> deg = 1 + sum(w); dis, inv
__global__ __launch_bounds__(256) void deg_kernel(const int* __restrict__ rowptr,
                                                  const int2* __restrict__ csr,
                                                  float* __restrict__ dis,
                                                  float* __restrict__ inv) {
  int b = blockIdx.y;
  int n = blockIdx.x * 256 + threadIdx.x;
  if (n >= NNODES) return;
  int start = rowptr[b * (NNODES + 1) + n];
  int end = rowptr[b * (NNODES + 1) + n + 1];
  float s = 1.0f;  // self-loop
  for (int k = start; k < end; ++k) s += __int_as_float(csr[k].y);
  dis[b * NNODES + n] = rsqrtf(s);
  inv[b * NNODES + n] = 1.0f / s;
}

// ===========================================================================
// per-layer gather + fused combine:
// out[n][j] = maybe_tanh( dis[n]*sum_k w_k*dis[src_k]*xw[src_k][j]
//                         + xw[n][j]*inv[n] + bias[j] )
// F threads per node; unroll 4 for memory-level parallelism.
// dis[src] is an 80KB/batch table -> L1/L2 broadcast hit.
// ===========================================================================
template <int F, bool TANH>
__global__ __launch_bounds__(256) void gather_kernel(
    const int* __restrict__ rowptr, const int2* __restrict__ csr,
    const float* __restrict__ dis, const float* __restrict__ inv,
    const float* __restrict__ xw, const float* __restrict__ bias,
    float* __restrict__ out) {
  constexpr int NPB = 256 / F;
  int b = blockIdx.y;
  int n = blockIdx.x * NPB + threadIdx.x / F;  // grid.x exact divisor
  int j = threadIdx.x & (F - 1);
  long long bn = (long long)b * NNODES + n;
  int start = rowptr[b * (NNODES + 1) + n];
  int end = rowptr[b * (NNODES + 1) + n + 1];
  const float* xwb = xw + (long long)b * NNODES * F;
  const float* disb = dis + (long long)b * NNODES;
  float acc0 = 0.0f, acc1 = 0.0f, acc2 = 0.0f, acc3 = 0.0f;
  int k = start;
  for (; k + 4 <= end; k += 4) {
    int2 p0 = csr[k];
    int2 p1 = csr[k + 1];
    int2 p2 = csr[k + 2];
    int2 p3 = csr[k + 3];
    acc0 += __int_as_float(p0.y) * disb[p0.x] * xwb[p0.x * F + j];
    acc1 += __int_as_float(p1.y) * disb[p1.x] * xwb[p1.x * F + j];
    acc2 += __int_as_float(p2.y) * disb[p2.x] * xwb[p2.x * F + j];
    acc3 += __int_as_float(p3.y) * disb[p3.x] * xwb[p3.x * F + j];
  }
  for (; k < end; ++k) {
    int2 p = csr[k];
    acc0 += __int_as_float(p.y) * disb[p.x] * xwb[p.x * F + j];
  }
  float self = xwb[n * F + j];
  float r = dis[bn] * ((acc0 + acc1) + (acc2 + acc3)) + self * inv[bn] + bias[j];
  out[bn * F + j] = TANH ? tanhf(r) : r;
}

// ===========================================================================
// dense kernels (unchanged)
// ===========================================================================
__device__ __forceinline__ float wave_reduce16(const float p[16], int lane) {
  float v8[8];
  {
    const bool hi = lane & 1;
#pragma unroll
    for (int q = 0; q < 8; ++q) {
      float keep = hi ? p[2 * q + 1] : p[2 * q];
      float give = hi ? p[2 * q] : p[2 * q + 1];
      v8[q] = keep + __shfl_xor(give, 1);
    }
  }
  float v4[4];
  {
    const bool hi = (lane >> 1) & 1;
#pragma unroll
    for (int q = 0; q < 4; ++q) {
      float keep = hi ? v8[2 * q + 1] : v8[2 * q];
      float give = hi ? v8[2 * q] : v8[2 * q + 1];
      v4[q] = keep + __shfl_xor(give, 2);
    }
  }
  float v2[2];
  {
    const bool hi = (lane >> 2) & 1;
#pragma unroll
    for (int q = 0; q < 2; ++q) {
      float keep = hi ? v4[2 * q + 1] : v4[2 * q];
      float give = hi ? v4[2 * q] : v4[2 * q + 1];
      v2[q] = keep + __shfl_xor(give, 4);
    }
  }
  float v1;
  {
    const bool hi = (lane >> 3) & 1;
    float keep = hi ? v2[1] : v2[0];
    float give = hi ? v2[0] : v2[1];
    v1 = keep + __shfl_xor(give, 8);
  }
  v1 += __shfl_xor(v1, 16);
  v1 += __shfl_xor(v1, 32);
  return v1;
}

__global__ __launch_bounds__(256) void mm1_kernel(
    const float* __restrict__ x, const float* __restrict__ W1,
    float* __restrict__ xw) {
  const int lane = threadIdx.x & 63;
  const int wib = threadIdx.x >> 6;
  const int wave = blockIdx.x * 4 + wib;
  const int nwaves = gridDim.x * 4;

  float wreg[64];
  {
    const float4* W4 = (const float4*)(W1 + lane * 64);
#pragma unroll
    for (int q = 0; q < 16; ++q) {
      float4 v = W4[q];
      wreg[q * 4 + 0] = v.x;
      wreg[q * 4 + 1] = v.y;
      wreg[q * 4 + 2] = v.z;
      wreg[q * 4 + 3] = v.w;
    }
  }
  const int nrows = NB * NNODES;
  for (int row = wave; row < nrows; row += nwaves) {
    float4 xv = ((const float4*)x)[(long long)row * 64 + lane];
    float p[16];
#pragma unroll
    for (int j = 0; j < 16; ++j) {
      p[j] = xv.x * wreg[j] + xv.y * wreg[16 + j] + xv.z * wreg[32 + j] +
             xv.w * wreg[48 + j];
    }
    float v = wave_reduce16(p, lane);
    if (lane < 16) xw[(long long)row * 16 + lane] = v;
  }
}

template <int FOUT>
__global__ __launch_bounds__(256) void mm_small_kernel(
    const float* __restrict__ h, const float* __restrict__ W,
    float* __restrict__ out) {
  __shared__ float Ws[16 * FOUT];
  for (int t = threadIdx.x; t < 16 * FOUT; t += 256) Ws[t] = W[t];
  __syncthreads();
  int idx = blockIdx.x * 256 + threadIdx.x;
  if (idx >= NB * NNODES * FOUT) return;
  int row = idx / FOUT;
  int j = idx & (FOUT - 1);
  const float4* hr = (const float4*)(h + (long long)row * 16);
  float hv[16];
#pragma unroll
  for (int q = 0; q < 4; ++q) {
    float4 v = hr[q];
    hv[q * 4 + 0] = v.x;
    hv[q * 4 + 1] = v.y;
    hv[q * 4 + 2] = v.z;
    hv[q * 4 + 3] = v.w;
  }
  float acc = 0.0f;
#pragma unroll
  for (int k = 0; k < 16; ++k) acc += hv[k] * Ws[k * FOUT + j];
  out[idx] = acc;
}

__global__ __launch_bounds__(256) void fc_kernel(
    const float* __restrict__ emb, const int* __restrict__ pos,
    const float* __restrict__ fcW1, const float* __restrict__ fcb1,
    const float* __restrict__ fcW2, const float* __restrict__ fcb2,
    const float* __restrict__ fcW3, const float* __restrict__ fcb3,
    float* __restrict__ out) {
  int b = blockIdx.x;
  int tid = threadIdx.x;
  __shared__ float flat[160];
  __shared__ float hb[128];
  if (tid < 160) {
    int p = tid / 32, j = tid & 31;
    int pv = pos[b * NP + p];
    float v;
    if (pv == -1) {
      v = -3.0f;  // -DEPTH
    } else {
      int node = pv < 0 ? 0 : (pv > NNODES - 1 ? NNODES - 1 : pv);
      v = emb[((long long)b * NNODES + node) * 32 + j];
    }
    flat[tid] = v;
  }
  __syncthreads();
  float acc1 = 0.0f;
  if (tid < 128) {
    acc1 = fcb1[tid];
#pragma unroll 8
    for (int k = 0; k < 160; ++k) acc1 += flat[k] * fcW1[k * 128 + tid];
    acc1 = tanhf(acc1);
  }
  __syncthreads();
  if (tid < 128) hb[tid] = acc1;
  __syncthreads();
  float acc2 = 0.0f;
  if (tid < 128) {
    acc2 = fcb2[tid];
#pragma unroll 8
    for (int k = 0; k < 128; ++k) acc2 += hb[k] * fcW2[k * 128 + tid];
    acc2 = tanhf(acc2);
  }
  __syncthreads();
  if (tid < 128) flat[tid] = acc2;
  __syncthreads();
  if (tid < NA) {
    float acc = fcb3[tid];
#pragma unroll 8
    for (int k = 0; k < 128; ++k) acc += flat[k] * fcW3[k * NA + tid];
    out[b * NA + tid] = acc;
  }
}

// ===========================================================================
extern "C" void kernel_launch(void* const* d_in, const int* in_sizes, int n_in,
                              void* d_out, int out_size, void* d_ws,
                              size_t ws_size, hipStream_t stream) {
  const float* x = (const float*)d_in[0];
  const int* ei = (const int*)d_in[1];
  const float* ew = (const float*)d_in[2];
  const int* pos = (const int*)d_in[3];
  const float* W1 = (const float*)d_in[4];
  const float* b1 = (const float*)d_in[5];
  const float* W2 = (const float*)d_in[6];
  const float* b2 = (const float*)d_in[7];
  const float* W3 = (const float*)d_in[8];
  const float* b3 = (const float*)d_in[9];
  const float* fcW1 = (const float*)d_in[10];
  const float* fcb1 = (const float*)d_in[11];
  const float* fcW2 = (const float*)d_in[12];
  const float* fcb2 = (const float*)d_in[13];
  const float* fcW3 = (const float*)d_in[14];
  const float* fcb3 = (const float*)d_in[15];
  float* out = (float*)d_out;

  const long long BN = (long long)NB * NNODES;  // 320000
  // workspace layout (prefix before csr is even #ints -> csr 8B aligned)
  int* cnt = (int*)d_ws;                       // BN (count, then cursor)
  int* rowptr = cnt + BN;                      // NB*(NNODES+1) = 320016
  float* dis = (float*)(rowptr + NB * (NNODES + 1));  // BN
  float* inv = dis + BN;                       // BN
  int2* csr = (int2*)(inv + BN);               // NB*NEDGES int2 = 40.96 MB
  float* bufA = (float*)(csr + (long long)NB * NEDGES);  // BN*32
  float* bufB = bufA + BN * 32;                // BN*32
  // total ~129 MB

  const dim3 egrid(NEDGES / 256, NB);  // 1250 x 16, exact

  // ---- CSR build (once; reused by all 3 layers) ----
  hipMemsetAsync(cnt, 0, BN * sizeof(int), stream);
  count_kernel<<<egrid, 256, 0, stream>>>(ei, cnt);
  scan_kernel<<<NB, 1024, 0, stream>>>(cnt, rowptr);
  hipMemsetAsync(cnt, 0, BN * sizeof(int), stream);  // reuse as cursor
  scatter_kernel<<<egrid, 256, 0, stream>>>(ei, ew, rowptr, cnt, csr);
  deg_kernel<<<dim3((NNODES + 255) / 256, NB), 256, 0, stream>>>(rowptr, csr,
                                                                 dis, inv);

  // ---- layer 1: x @ W1 -> 16, gather+combine+tanh ----
  mm1_kernel<<<4096, 256, 0, stream>>>(x, W1, bufA);
  gather_kernel<16, true><<<dim3(NNODES / 16, NB), 256, 0, stream>>>(
      rowptr, csr, dis, inv, bufA, b1, bufB);

  // ---- layer 2 ----
  mm_small_kernel<16><<<(int)(BN * 16 / 256), 256, 0, stream>>>(bufB, W2, bufA);
  gather_kernel<16, true><<<dim3(NNODES / 16, NB), 256, 0, stream>>>(
      rowptr, csr, dis, inv, bufA, b2, bufB);

  // ---- layer 3 ----
  mm_small_kernel<32><<<(int)(BN * 32 / 256), 256, 0, stream>>>(bufB, W3, bufA);
  gather_kernel<32, false><<<dim3(NNODES / 8, NB), 256, 0, stream>>>(
      rowptr, csr, dis, inv, bufA, b3, bufB);

  // ---- gather + MLP head ----
  fc_kernel<<<NB, 256, 0, stream>>>(bufB, pos, fcW1, fcb1, fcW2, fcb2, fcW3,
                                    fcb3, out);
}

// Round 10
// 1275.054 us; speedup vs baseline: 1.2556x; 1.0739x over previous
//
#include <hip/hip_runtime.h>

#define NNODES 20000
#define NEDGES 320000
#define NB 16
#define FIN 256
#define NP 5
#define NA 5
#define NBINS 32
#define BINSPAN (NNODES / NBINS)  // 625
#define EPB 2560                  // edges per bin_stage block; 125 blocks

// ===========================================================================
// CSR build: count -> scan -> binned two-pass scatter -> deg walk.
// ===========================================================================
__global__ __launch_bounds__(256) void count_kernel(const int* __restrict__ ei,
                                                    int* __restrict__ cnt) {
  int b = blockIdx.y;
  int e = blockIdx.x * 256 + threadIdx.x;  // grid.x = NEDGES/256 exact
  int dst = ei[b * 2 * NEDGES + NEDGES + e];
  atomicAdd(&cnt[b * NNODES + dst], 1);
}

// per-batch exclusive scan of cnt -> rowptr (global offsets include b*NEDGES)
__global__ __launch_bounds__(1024) void scan_kernel(const int* __restrict__ cnt,
                                                    int* __restrict__ rowptr) {
  int b = blockIdx.x;
  int tid = threadIdx.x;
  int lane = tid & 63, wid = tid >> 6;
  __shared__ int wsum[16];
  int carry = 0;
  for (int base = 0; base <= NNODES; base += 1024) {
    int i = base + tid;
    int v = (i < NNODES) ? cnt[b * NNODES + i] : 0;
    int x = v;
#pragma unroll
    for (int off = 1; off < 64; off <<= 1) {
      int y = __shfl_up(x, off);
      if (lane >= off) x += y;
    }
    if (lane == 63) wsum[wid] = x;
    __syncthreads();
    if (wid == 0) {
      int s = (lane < 16) ? wsum[lane] : 0;
#pragma unroll
      for (int off = 1; off < 16; off <<= 1) {
        int y = __shfl_up(s, off);
        if (lane >= off) s += y;
      }
      if (lane < 16) wsum[lane] = s;
    }
    __syncthreads();
    int wpre = (wid == 0) ? 0 : wsum[wid - 1];
    int excl = x + wpre - v;
    if (i <= NNODES) rowptr[b * (NNODES + 1) + i] = b * NEDGES + carry + excl;
    carry += wsum[15];
    __syncthreads();
  }
}

// init per-node cursor (=rowptr starts) and per-(b,bin) staging cursor
__global__ __launch_bounds__(256) void curinit_kernel(
    const int* __restrict__ rowptr, int* __restrict__ cur,
    int* __restrict__ bincur) {
  int i = blockIdx.x * 256 + threadIdx.x;
  if (i < NB * NNODES) {
    int b = i / NNODES, n = i - b * NNODES;
    cur[i] = rowptr[b * (NNODES + 1) + n];
  }
  if (i < NB * NBINS) {
    int b = i >> 5, k = i & (NBINS - 1);
    bincur[i] = rowptr[b * (NNODES + 1) + k * BINSPAN];
  }
}

// Pass A: stage edges bin-segmented (bins = contiguous dst ranges, whose
// segment bases are rowptr values). Coalesced block-chunk writes.
__global__ __launch_bounds__(256) void bin_stage_kernel(
    const int* __restrict__ ei, const float* __restrict__ ew,
    int* __restrict__ bincur, int2* __restrict__ stage) {
  int b = blockIdx.y;
  int base = blockIdx.x * EPB;
  int tid = threadIdx.x;
  __shared__ int hist[NBINS], sbase[NBINS], lcur[NBINS];
  if (tid < NBINS) hist[tid] = 0;
  __syncthreads();
  const int* dstp = ei + b * 2 * NEDGES + NEDGES;
  for (int e = base + tid; e < base + EPB; e += 256)
    atomicAdd(&hist[dstp[e] / BINSPAN], 1);
  __syncthreads();
  if (tid < NBINS) {
    sbase[tid] = atomicAdd(&bincur[b * NBINS + tid], hist[tid]);
    lcur[tid] = 0;
  }
  __syncthreads();
  const int* srcp = ei + b * 2 * NEDGES;
  const float* ewb = ew + b * NEDGES;
  for (int e = base + tid; e < base + EPB; e += 256) {
    int dst = dstp[e];
    int bin = dst / BINSPAN;
    int slot = atomicAdd(&lcur[bin], 1);
    stage[sbase[bin] + slot] =
        make_int2(srcp[e] | (dst << 15), __float_as_int(ewb[e]));
  }
}

// Pass B: consecutive threads handle same-bin staged edges -> csr writes land
// in an ~80KB window (625 nodes * avg16 * 8B): lines filled before eviction.
__global__ __launch_bounds__(256) void bin_scatter_kernel(
    const int2* __restrict__ stage, int* __restrict__ cur,
    int2* __restrict__ csr) {
  int b = blockIdx.y;
  int e = blockIdx.x * 256 + threadIdx.x;
  int2 s = stage[b * NEDGES + e];
  int dst = s.x >> 15;
  int src = s.x & 0x7FFF;
  int pos = atomicAdd(&cur[b * NNODES + dst], 1);
  csr[pos] = make_int2(src, s.y);
}

// per-node walk of contiguous CSR range -> deg = 1 + sum(w); dis, inv
__global__ __launch_bounds__(256) void deg_kernel(const int* __restrict__ rowptr,
                                                  const int2* __restrict__ csr,
                                                  float* __restrict__ dis,
                                                  float* __restrict__ inv) {
  int b = blockIdx.y;
  int n = blockIdx.x * 256 + threadIdx.x;
  if (n >= NNODES) return;
  int start = rowptr[b * (NNODES + 1) + n];
  int end = rowptr[b * (NNODES + 1) + n + 1];
  float s = 1.0f;  // self-loop
  for (int k = start; k < end; ++k) s += __int_as_float(csr[k].y);
  dis[b * NNODES + n] = rsqrtf(s);
  inv[b * NNODES + n] = 1.0f / s;
}

// ===========================================================================
// gather: agg[n][j] = dis[n]*sum_k w_k*dis[src_k]*h[src_k][j] + h[n][j]*inv[n]
//         (+ bias[j], tanh when fused for layer 1)
// ===========================================================================
template <int F, bool TANH, bool HASB>
__global__ __launch_bounds__(256) void gather_kernel(
    const int* __restrict__ rowptr, const int2* __restrict__ csr,
    const float* __restrict__ dis, const float* __restrict__ inv,
    const float* __restrict__ xw, const float* __restrict__ bias,
    float* __restrict__ out) {
  constexpr int NPB = 256 / F;
  int b = blockIdx.y;
  int n = blockIdx.x * NPB + threadIdx.x / F;
  int j = threadIdx.x & (F - 1);
  long long bn = (long long)b * NNODES + n;
  int start = rowptr[b * (NNODES + 1) + n];
  int end = rowptr[b * (NNODES + 1) + n + 1];
  const float* xwb = xw + (long long)b * NNODES * F;
  const float* disb = dis + (long long)b * NNODES;
  float acc0 = 0.0f, acc1 = 0.0f, acc2 = 0.0f, acc3 = 0.0f;
  int k = start;
  for (; k + 4 <= end; k += 4) {
    int2 p0 = csr[k];
    int2 p1 = csr[k + 1];
    int2 p2 = csr[k + 2];
    int2 p3 = csr[k + 3];
    acc0 += __int_as_float(p0.y) * disb[p0.x] * xwb[p0.x * F + j];
    acc1 += __int_as_float(p1.y) * disb[p1.x] * xwb[p1.x * F + j];
    acc2 += __int_as_float(p2.y) * disb[p2.x] * xwb[p2.x * F + j];
    acc3 += __int_as_float(p3.y) * disb[p3.x] * xwb[p3.x * F + j];
  }
  for (; k < end; ++k) {
    int2 p = csr[k];
    acc0 += __int_as_float(p.y) * disb[p.x] * xwb[p.x * F + j];
  }
  float r = dis[bn] * ((acc0 + acc1) + (acc2 + acc3)) +
            xwb[n * F + j] * inv[bn];
  if (HASB) r += bias[j];
  out[bn * F + j] = TANH ? tanhf(r) : r;
}

// ===========================================================================
// mmfuse: out[row][j] = maybe_tanh(agg[row][0..15] @ W[16][FOUT] + b[j])
// (aggregate-then-transform: valid by linearity of the GCN aggregation)
// ===========================================================================
template <int FOUT, bool TANH>
__global__ __launch_bounds__(256) void mmfuse_kernel(
    const float* __restrict__ h, const float* __restrict__ W,
    const float* __restrict__ bias, float* __restrict__ out) {
  __shared__ float Ws[16 * FOUT];
  __shared__ float Bs[FOUT];
  for (int t = threadIdx.x; t < 16 * FOUT; t += 256) Ws[t] = W[t];
  if (threadIdx.x < FOUT) Bs[threadIdx.x] = bias[threadIdx.x];
  __syncthreads();
  int idx = blockIdx.x * 256 + threadIdx.x;
  if (idx >= NB * NNODES * FOUT) return;
  int row = idx / FOUT;
  int j = idx & (FOUT - 1);
  const float4* hr = (const float4*)(h + (long long)row * 16);
  float hv[16];
#pragma unroll
  for (int q = 0; q < 4; ++q) {
    float4 v = hr[q];
    hv[q * 4 + 0] = v.x;
    hv[q * 4 + 1] = v.y;
    hv[q * 4 + 2] = v.z;
    hv[q * 4 + 3] = v.w;
  }
  float acc = Bs[j];
#pragma unroll
  for (int k = 0; k < 16; ++k) acc += hv[k] * Ws[k * FOUT + j];
  out[idx] = TANH ? tanhf(acc) : acc;
}

// ===========================================================================
// dense layer-1 matmul (unchanged)
// ===========================================================================
__device__ __forceinline__ float wave_reduce16(const float p[16], int lane) {
  float v8[8];
  {
    const bool hi = lane & 1;
#pragma unroll
    for (int q = 0; q < 8; ++q) {
      float keep = hi ? p[2 * q + 1] : p[2 * q];
      float give = hi ? p[2 * q] : p[2 * q + 1];
      v8[q] = keep + __shfl_xor(give, 1);
    }
  }
  float v4[4];
  {
    const bool hi = (lane >> 1) & 1;
#pragma unroll
    for (int q = 0; q < 4; ++q) {
      float keep = hi ? v8[2 * q + 1] : v8[2 * q];
      float give = hi ? v8[2 * q] : v8[2 * q + 1];
      v4[q] = keep + __shfl_xor(give, 2);
    }
  }
  float v2[2];
  {
    const bool hi = (lane >> 2) & 1;
#pragma unroll
    for (int q = 0; q < 2; ++q) {
      float keep = hi ? v4[2 * q + 1] : v4[2 * q];
      float give = hi ? v4[2 * q] : v4[2 * q + 1];
      v2[q] = keep + __shfl_xor(give, 4);
    }
  }
  float v1;
  {
    const bool hi = (lane >> 3) & 1;
    float keep = hi ? v2[1] : v2[0];
    float give = hi ? v2[0] : v2[1];
    v1 = keep + __shfl_xor(give, 8);
  }
  v1 += __shfl_xor(v1, 16);
  v1 += __shfl_xor(v1, 32);
  return v1;
}

__global__ __launch_bounds__(256) void mm1_kernel(
    const float* __restrict__ x, const float* __restrict__ W1,
    float* __restrict__ xw) {
  const int lane = threadIdx.x & 63;
  const int wib = threadIdx.x >> 6;
  const int wave = blockIdx.x * 4 + wib;
  const int nwaves = gridDim.x * 4;

  float wreg[64];
  {
    const float4* W4 = (const float4*)(W1 + lane * 64);
#pragma unroll
    for (int q = 0; q < 16; ++q) {
      float4 v = W4[q];
      wreg[q * 4 + 0] = v.x;
      wreg[q * 4 + 1] = v.y;
      wreg[q * 4 + 2] = v.z;
      wreg[q * 4 + 3] = v.w;
    }
  }
  const int nrows = NB * NNODES;
  for (int row = wave; row < nrows; row += nwaves) {
    float4 xv = ((const float4*)x)[(long long)row * 64 + lane];
    float p[16];
#pragma unroll
    for (int j = 0; j < 16; ++j) {
      p[j] = xv.x * wreg[j] + xv.y * wreg[16 + j] + xv.z * wreg[32 + j] +
             xv.w * wreg[48 + j];
    }
    float v = wave_reduce16(p, lane);
    if (lane < 16) xw[(long long)row * 16 + lane] = v;
  }
}

__global__ __launch_bounds__(256) void fc_kernel(
    const float* __restrict__ emb, const int* __restrict__ pos,
    const float* __restrict__ fcW1, const float* __restrict__ fcb1,
    const float* __restrict__ fcW2, const float* __restrict__ fcb2,
    const float* __restrict__ fcW3, const float* __restrict__ fcb3,
    float* __restrict__ out) {
  int b = blockIdx.x;
  int tid = threadIdx.x;
  __shared__ float flat[160];
  __shared__ float hb[128];
  if (tid < 160) {
    int p = tid / 32, j = tid & 31;
    int pv = pos[b * NP + p];
    float v;
    if (pv == -1) {
      v = -3.0f;  // -DEPTH
    } else {
      int node = pv < 0 ? 0 : (pv > NNODES - 1 ? NNODES - 1 : pv);
      v = emb[((long long)b * NNODES + node) * 32 + j];
    }
    flat[tid] = v;
  }
  __syncthreads();
  float acc1 = 0.0f;
  if (tid < 128) {
    acc1 = fcb1[tid];
#pragma unroll 8
    for (int k = 0; k < 160; ++k) acc1 += flat[k] * fcW1[k * 128 + tid];
    acc1 = tanhf(acc1);
  }
  __syncthreads();
  if (tid < 128) hb[tid] = acc1;
  __syncthreads();
  float acc2 = 0.0f;
  if (tid < 128) {
    acc2 = fcb2[tid];
#pragma unroll 8
    for (int k = 0; k < 128; ++k) acc2 += hb[k] * fcW2[k * 128 + tid];
    acc2 = tanhf(acc2);
  }
  __syncthreads();
  if (tid < 128) flat[tid] = acc2;
  __syncthreads();
  if (tid < NA) {
    float acc = fcb3[tid];
#pragma unroll 8
    for (int k = 0; k < 128; ++k) acc += flat[k] * fcW3[k * NA + tid];
    out[b * NA + tid] = acc;
  }
}

// ===========================================================================
extern "C" void kernel_launch(void* const* d_in, const int* in_sizes, int n_in,
                              void* d_out, int out_size, void* d_ws,
                              size_t ws_size, hipStream_t stream) {
  const float* x = (const float*)d_in[0];
  const int* ei = (const int*)d_in[1];
  const float* ew = (const float*)d_in[2];
  const int* pos = (const int*)d_in[3];
  const float* W1 = (const float*)d_in[4];
  const float* b1 = (const float*)d_in[5];
  const float* W2 = (const float*)d_in[6];
  const float* b2 = (const float*)d_in[7];
  const float* W3 = (const float*)d_in[8];
  const float* b3 = (const float*)d_in[9];
  const float* fcW1 = (const float*)d_in[10];
  const float* fcb1 = (const float*)d_in[11];
  const float* fcW2 = (const float*)d_in[12];
  const float* fcb2 = (const float*)d_in[13];
  const float* fcW3 = (const float*)d_in[14];
  const float* fcb3 = (const float*)d_in[15];
  float* out = (float*)d_out;

  const long long BN = (long long)NB * NNODES;  // 320000
  // workspace (int-granular; every 8B object lands on even-int offset)
  int* cnt = (int*)d_ws;                       // BN
  int* rowptr = cnt + BN;                      // NB*(NNODES+1)
  int* cur = rowptr + NB * (NNODES + 1);       // BN
  int* bincur = cur + BN;                      // NB*NBINS = 512
  float* dis = (float*)(bincur + NB * NBINS);  // BN
  float* inv = dis + BN;                       // BN
  int2* csr = (int2*)(inv + BN);               // NB*NEDGES int2 = 41 MB
  float* bufA = (float*)(csr + (long long)NB * NEDGES);  // BN*32
  float* bufB = bufA + BN * 32;                // BN*32
  int2* stage = (int2*)bufA;                   // alias: dead before mm1
  // total ~130 MB

  const dim3 egrid(NEDGES / 256, NB);  // 1250 x 16

  // ---- CSR build ----
  hipMemsetAsync(cnt, 0, BN * sizeof(int), stream);
  count_kernel<<<egrid, 256, 0, stream>>>(ei, cnt);
  scan_kernel<<<NB, 1024, 0, stream>>>(cnt, rowptr);
  curinit_kernel<<<(int)((BN + 255) / 256), 256, 0, stream>>>(rowptr, cur,
                                                              bincur);
  bin_stage_kernel<<<dim3(NEDGES / EPB, NB), 256, 0, stream>>>(ei, ew, bincur,
                                                               stage);
  bin_scatter_kernel<<<egrid, 256, 0, stream>>>(stage, cur, csr);
  deg_kernel<<<dim3((NNODES + 255) / 256, NB), 256, 0, stream>>>(rowptr, csr,
                                                                 dis, inv);

  // ---- layer 1: x @ W1 -> 16, gather(+bias+tanh) ----
  mm1_kernel<<<4096, 256, 0, stream>>>(x, W1, bufA);
  gather_kernel<16, true, true><<<dim3(NNODES / 16, NB), 256, 0, stream>>>(
      rowptr, csr, dis, inv, bufA, b1, bufB);

  // ---- layer 2: aggregate h1 (16) then W2+b2+tanh ----
  gather_kernel<16, false, false><<<dim3(NNODES / 16, NB), 256, 0, stream>>>(
      rowptr, csr, dis, inv, bufB, b2, bufA);
  mmfuse_kernel<16, true><<<(int)(BN * 16 / 256), 256, 0, stream>>>(bufA, W2,
                                                                    b2, bufB);

  // ---- layer 3: aggregate h2 (16) then W3+b3 ----
  gather_kernel<16, false, false><<<dim3(NNODES / 16, NB), 256, 0, stream>>>(
      rowptr, csr, dis, inv, bufB, b3, bufA);
  mmfuse_kernel<32, false><<<(int)(BN * 32 / 256), 256, 0, stream>>>(bufA, W3,
                                                                     b3, bufB);

  // ---- gather + MLP head ----
  fc_kernel<<<NB, 256, 0, stream>>>(bufB, pos, fcW1, fcb1, fcW2, fcb2, fcW3,
                                    fcb3, out);
}

// Round 11
// 961.962 us; speedup vs baseline: 1.6643x; 1.3255x over previous
//
#include <hip/hip_runtime.h>

#define NNODES 20000
#define NEDGES 320000
#define NB 16
#define FIN 256
#define NP 5
#define NA 5
#define NBINS 32
#define BINSPAN (NNODES / NBINS)  // 625
#define EPB 2560                  // edges per bin_stage block; 125 blocks
#define CAP 16384                 // stage capacity per (batch,bin); exp 10000±99

// ===========================================================================
// Pass A: stage edges into fixed-capacity dst-range bins (no rowptr dep).
// Per-block LDS histogram -> one global atomic per (block,bin) chunk reserve.
// ===========================================================================
__global__ __launch_bounds__(256) void bin_stage_kernel(
    const int* __restrict__ ei, const float* __restrict__ ew,
    int* __restrict__ bincur, int2* __restrict__ stage) {
  int b = blockIdx.y;
  int base = blockIdx.x * EPB;
  int tid = threadIdx.x;
  __shared__ int hist[NBINS], sbase[NBINS], lcur[NBINS];
  if (tid < NBINS) hist[tid] = 0;
  __syncthreads();
  const int* dstp = ei + b * 2 * NEDGES + NEDGES;
  for (int e = base + tid; e < base + EPB; e += 256)
    atomicAdd(&hist[dstp[e] / BINSPAN], 1);
  __syncthreads();
  if (tid < NBINS) {
    sbase[tid] = atomicAdd(&bincur[b * NBINS + tid], hist[tid]);
    lcur[tid] = 0;
  }
  __syncthreads();
  const int* srcp = ei + b * 2 * NEDGES;
  const float* ewb = ew + b * NEDGES;
  for (int e = base + tid; e < base + EPB; e += 256) {
    int dst = dstp[e];
    int bin = dst / BINSPAN;
    int slot = sbase[bin] + atomicAdd(&lcur[bin], 1);
    if (slot < CAP)  // overflow guard (binomial tail; never hit in practice)
      stage[(b * NBINS + bin) * CAP + slot] =
          make_int2(srcp[e] | (dst << 15), __float_as_int(ewb[e]));
  }
}

// tiny glue: per-batch exclusive scan of 32 bin sizes -> global CSR bin bases
__global__ __launch_bounds__(64) void binbase_kernel(
    const int* __restrict__ bincur, int* __restrict__ binbase,
    int* __restrict__ rowptr) {
  int b = threadIdx.x;
  if (b < NB) {
    int c = b * NEDGES;
    for (int k = 0; k < NBINS; ++k) {
      int s = min(bincur[b * NBINS + k], CAP);
      binbase[b * NBINS + k] = c;
      c += s;
    }
    rowptr[b * (NNODES + 1) + NNODES] = b * NEDGES + NEDGES;
  }
}

// ===========================================================================
// Pass B: one block per (batch,bin). All bookkeeping in LDS:
// histogram 625 nodes -> local scan -> rowptr/dis/inv writes -> place edges
// into the bin's contiguous ~80KB CSR window. Zero global atomics.
// ===========================================================================
__global__ __launch_bounds__(256) void bin_csr_kernel(
    const int2* __restrict__ stage, const int* __restrict__ bincur,
    const int* __restrict__ binbase, int* __restrict__ rowptr,
    float* __restrict__ dis, float* __restrict__ inv,
    int2* __restrict__ csr) {
  int bin = blockIdx.x;
  int b = blockIdx.y;
  int tid = threadIdx.x;
  int lane = tid & 63, wid = tid >> 6;
  const int lo = bin * BINSPAN;
  const int idx = b * NBINS + bin;
  const int segn = min(bincur[idx], CAP);
  const int2* seg = stage + (long long)idx * CAP;
  const int gbase = binbase[idx];

  __shared__ int h[BINSPAN];      // counts, then placement cursors
  __shared__ float sw[BINSPAN];   // per-node sum of w
  __shared__ int excl[BINSPAN];   // local exclusive prefix
  __shared__ int wls[4], wbase[4];

  for (int i = tid; i < BINSPAN; i += 256) {
    h[i] = 0;
    sw[i] = 0.0f;
  }
  __syncthreads();

  // pass 1: LDS histogram + weighted degree
  for (int i = tid; i < segn; i += 256) {
    int2 s = seg[i];
    int dl = (s.x >> 15) - lo;
    atomicAdd(&h[dl], 1);
    atomicAdd(&sw[dl], __int_as_float(s.y));
  }
  __syncthreads();

  // local exclusive scan of h[0..624]: 3 nodes per thread + wave/block scan
  int i0 = 3 * tid;
  int a0 = (i0 + 0 < BINSPAN) ? h[i0 + 0] : 0;
  int a1 = (i0 + 1 < BINSPAN) ? h[i0 + 1] : 0;
  int a2 = (i0 + 2 < BINSPAN) ? h[i0 + 2] : 0;
  int mysum = a0 + a1 + a2;
  int x = mysum;
#pragma unroll
  for (int off = 1; off < 64; off <<= 1) {
    int y = __shfl_up(x, off);
    if (lane >= off) x += y;
  }
  if (lane == 63) wls[wid] = x;
  __syncthreads();
  if (tid == 0) {
    int c = 0;
#pragma unroll
    for (int k = 0; k < 4; ++k) {
      wbase[k] = c;
      c += wls[k];
    }
  }
  __syncthreads();
  int myexcl = x - mysum + wbase[wid];
  if (i0 + 0 < BINSPAN) excl[i0 + 0] = myexcl;
  if (i0 + 1 < BINSPAN) excl[i0 + 1] = myexcl + a0;
  if (i0 + 2 < BINSPAN) excl[i0 + 2] = myexcl + a0 + a1;
  __syncthreads();

  // rowptr + dis/inv for this bin's nodes (coalesced)
  for (int i = tid; i < BINSPAN; i += 256) {
    rowptr[b * (NNODES + 1) + lo + i] = gbase + excl[i];
    float d = sw[i] + 1.0f;  // self-loop
    dis[b * NNODES + lo + i] = rsqrtf(d);
    inv[b * NNODES + lo + i] = 1.0f / d;
  }
  __syncthreads();
  for (int i = tid; i < BINSPAN; i += 256) h[i] = 0;  // reuse as cursor
  __syncthreads();

  // pass 2: place edges into the contiguous CSR window
  for (int i = tid; i < segn; i += 256) {
    int2 s = seg[i];
    int dl = (s.x >> 15) - lo;
    int pos = excl[dl] + atomicAdd(&h[dl], 1);
    csr[gbase + pos] = make_int2(s.x & 0x7FFF, s.y);
  }
}

// ===========================================================================
// gather: agg[n][j] = dis[n]*sum_k w_k*dis[src_k]*h[src_k][j] + h[n][j]*inv[n]
//         (+ bias[j], tanh when fused for layer 1)
// ===========================================================================
template <int F, bool TANH, bool HASB>
__global__ __launch_bounds__(256) void gather_kernel(
    const int* __restrict__ rowptr, const int2* __restrict__ csr,
    const float* __restrict__ dis, const float* __restrict__ inv,
    const float* __restrict__ xw, const float* __restrict__ bias,
    float* __restrict__ out) {
  constexpr int NPB = 256 / F;
  int b = blockIdx.y;
  int n = blockIdx.x * NPB + threadIdx.x / F;
  int j = threadIdx.x & (F - 1);
  long long bn = (long long)b * NNODES + n;
  int start = rowptr[b * (NNODES + 1) + n];
  int end = rowptr[b * (NNODES + 1) + n + 1];
  const float* xwb = xw + (long long)b * NNODES * F;
  const float* disb = dis + (long long)b * NNODES;
  float acc0 = 0.0f, acc1 = 0.0f, acc2 = 0.0f, acc3 = 0.0f;
  int k = start;
  for (; k + 4 <= end; k += 4) {
    int2 p0 = csr[k];
    int2 p1 = csr[k + 1];
    int2 p2 = csr[k + 2];
    int2 p3 = csr[k + 3];
    acc0 += __int_as_float(p0.y) * disb[p0.x] * xwb[p0.x * F + j];
    acc1 += __int_as_float(p1.y) * disb[p1.x] * xwb[p1.x * F + j];
    acc2 += __int_as_float(p2.y) * disb[p2.x] * xwb[p2.x * F + j];
    acc3 += __int_as_float(p3.y) * disb[p3.x] * xwb[p3.x * F + j];
  }
  for (; k < end; ++k) {
    int2 p = csr[k];
    acc0 += __int_as_float(p.y) * disb[p.x] * xwb[p.x * F + j];
  }
  float r = dis[bn] * ((acc0 + acc1) + (acc2 + acc3)) +
            xwb[n * F + j] * inv[bn];
  if (HASB) r += bias[j];
  out[bn * F + j] = TANH ? tanhf(r) : r;
}

// ===========================================================================
// mmfuse: out[row][j] = maybe_tanh(agg[row][0..15] @ W[16][FOUT] + b[j])
// (aggregate-then-transform: valid by linearity of the GCN aggregation)
// ===========================================================================
template <int FOUT, bool TANH>
__global__ __launch_bounds__(256) void mmfuse_kernel(
    const float* __restrict__ h, const float* __restrict__ W,
    const float* __restrict__ bias, float* __restrict__ out) {
  __shared__ float Ws[16 * FOUT];
  __shared__ float Bs[FOUT];
  for (int t = threadIdx.x; t < 16 * FOUT; t += 256) Ws[t] = W[t];
  if (threadIdx.x < FOUT) Bs[threadIdx.x] = bias[threadIdx.x];
  __syncthreads();
  int idx = blockIdx.x * 256 + threadIdx.x;
  if (idx >= NB * NNODES * FOUT) return;
  int row = idx / FOUT;
  int j = idx & (FOUT - 1);
  const float4* hr = (const float4*)(h + (long long)row * 16);
  float hv[16];
#pragma unroll
  for (int q = 0; q < 4; ++q) {
    float4 v = hr[q];
    hv[q * 4 + 0] = v.x;
    hv[q * 4 + 1] = v.y;
    hv[q * 4 + 2] = v.z;
    hv[q * 4 + 3] = v.w;
  }
  float acc = Bs[j];
#pragma unroll
  for (int k = 0; k < 16; ++k) acc += hv[k] * Ws[k * FOUT + j];
  out[idx] = TANH ? tanhf(acc) : acc;
}

// ===========================================================================
// dense layer-1 matmul (unchanged)
// ===========================================================================
__device__ __forceinline__ float wave_reduce16(const float p[16], int lane) {
  float v8[8];
  {
    const bool hi = lane & 1;
#pragma unroll
    for (int q = 0; q < 8; ++q) {
      float keep = hi ? p[2 * q + 1] : p[2 * q];
      float give = hi ? p[2 * q] : p[2 * q + 1];
      v8[q] = keep + __shfl_xor(give, 1);
    }
  }
  float v4[4];
  {
    const bool hi = (lane >> 1) & 1;
#pragma unroll
    for (int q = 0; q < 4; ++q) {
      float keep = hi ? v8[2 * q + 1] : v8[2 * q];
      float give = hi ? v8[2 * q] : v8[2 * q + 1];
      v4[q] = keep + __shfl_xor(give, 2);
    }
  }
  float v2[2];
  {
    const bool hi = (lane >> 2) & 1;
#pragma unroll
    for (int q = 0; q < 2; ++q) {
      float keep = hi ? v4[2 * q + 1] : v4[2 * q];
      float give = hi ? v4[2 * q] : v4[2 * q + 1];
      v2[q] = keep + __shfl_xor(give, 4);
    }
  }
  float v1;
  {
    const bool hi = (lane >> 3) & 1;
    float keep = hi ? v2[1] : v2[0];
    float give = hi ? v2[0] : v2[1];
    v1 = keep + __shfl_xor(give, 8);
  }
  v1 += __shfl_xor(v1, 16);
  v1 += __shfl_xor(v1, 32);
  return v1;
}

__global__ __launch_bounds__(256) void mm1_kernel(
    const float* __restrict__ x, const float* __restrict__ W1,
    float* __restrict__ xw) {
  const int lane = threadIdx.x & 63;
  const int wib = threadIdx.x >> 6;
  const int wave = blockIdx.x * 4 + wib;
  const int nwaves = gridDim.x * 4;

  float wreg[64];
  {
    const float4* W4 = (const float4*)(W1 + lane * 64);
#pragma unroll
    for (int q = 0; q < 16; ++q) {
      float4 v = W4[q];
      wreg[q * 4 + 0] = v.x;
      wreg[q * 4 + 1] = v.y;
      wreg[q * 4 + 2] = v.z;
      wreg[q * 4 + 3] = v.w;
    }
  }
  const int nrows = NB * NNODES;
  for (int row = wave; row < nrows; row += nwaves) {
    float4 xv = ((const float4*)x)[(long long)row * 64 + lane];
    float p[16];
#pragma unroll
    for (int j = 0; j < 16; ++j) {
      p[j] = xv.x * wreg[j] + xv.y * wreg[16 + j] + xv.z * wreg[32 + j] +
             xv.w * wreg[48 + j];
    }
    float v = wave_reduce16(p, lane);
    if (lane < 16) xw[(long long)row * 16 + lane] = v;
  }
}

__global__ __launch_bounds__(256) void fc_kernel(
    const float* __restrict__ emb, const int* __restrict__ pos,
    const float* __restrict__ fcW1, const float* __restrict__ fcb1,
    const float* __restrict__ fcW2, const float* __restrict__ fcb2,
    const float* __restrict__ fcW3, const float* __restrict__ fcb3,
    float* __restrict__ out) {
  int b = blockIdx.x;
  int tid = threadIdx.x;
  __shared__ float flat[160];
  __shared__ float hb[128];
  if (tid < 160) {
    int p = tid / 32, j = tid & 31;
    int pv = pos[b * NP + p];
    float v;
    if (pv == -1) {
      v = -3.0f;  // -DEPTH
    } else {
      int node = pv < 0 ? 0 : (pv > NNODES - 1 ? NNODES - 1 : pv);
      v = emb[((long long)b * NNODES + node) * 32 + j];
    }
    flat[tid] = v;
  }
  __syncthreads();
  float acc1 = 0.0f;
  if (tid < 128) {
    acc1 = fcb1[tid];
#pragma unroll 8
    for (int k = 0; k < 160; ++k) acc1 += flat[k] * fcW1[k * 128 + tid];
    acc1 = tanhf(acc1);
  }
  __syncthreads();
  if (tid < 128) hb[tid] = acc1;
  __syncthreads();
  float acc2 = 0.0f;
  if (tid < 128) {
    acc2 = fcb2[tid];
#pragma unroll 8
    for (int k = 0; k < 128; ++k) acc2 += hb[k] * fcW2[k * 128 + tid];
    acc2 = tanhf(acc2);
  }
  __syncthreads();
  if (tid < 128) flat[tid] = acc2;
  __syncthreads();
  if (tid < NA) {
    float acc = fcb3[tid];
#pragma unroll 8
    for (int k = 0; k < 128; ++k) acc += flat[k] * fcW3[k * NA + tid];
    out[b * NA + tid] = acc;
  }
}

// ===========================================================================
extern "C" void kernel_launch(void* const* d_in, const int* in_sizes, int n_in,
                              void* d_out, int out_size, void* d_ws,
                              size_t ws_size, hipStream_t stream) {
  const float* x = (const float*)d_in[0];
  const int* ei = (const int*)d_in[1];
  const float* ew = (const float*)d_in[2];
  const int* pos = (const int*)d_in[3];
  const float* W1 = (const float*)d_in[4];
  const float* b1 = (const float*)d_in[5];
  const float* W2 = (const float*)d_in[6];
  const float* b2 = (const float*)d_in[7];
  const float* W3 = (const float*)d_in[8];
  const float* b3 = (const float*)d_in[9];
  const float* fcW1 = (const float*)d_in[10];
  const float* fcb1 = (const float*)d_in[11];
  const float* fcW2 = (const float*)d_in[12];
  const float* fcb2 = (const float*)d_in[13];
  const float* fcW3 = (const float*)d_in[14];
  const float* fcb3 = (const float*)d_in[15];
  float* out = (float*)d_out;

  const long long BN = (long long)NB * NNODES;  // 320000
  // workspace (int-granular; every 8B object lands on even-int offset)
  int* rowptr = (int*)d_ws;                    // NB*(NNODES+1)
  int* bincur = rowptr + NB * (NNODES + 1);    // NB*NBINS
  int* binbase = bincur + NB * NBINS;          // NB*NBINS
  float* dis = (float*)(binbase + NB * NBINS); // BN
  float* inv = dis + BN;                       // BN
  int2* csr = (int2*)(inv + BN);               // NB*NEDGES int2 = 41 MB
  float* bufA = (float*)(csr + (long long)NB * NEDGES);  // BN*32
  float* bufB = bufA + BN * 32;                // BN*32
  int2* stage = (int2*)bufA;  // alias: NB*NBINS*CAP*8B = 67MB < bufA+bufB 82MB
  // total ~128 MB

  // ---- CSR build: stage -> binbase -> per-bin LDS count/scan/place ----
  hipMemsetAsync(bincur, 0, NB * NBINS * sizeof(int), stream);
  bin_stage_kernel<<<dim3(NEDGES / EPB, NB), 256, 0, stream>>>(ei, ew, bincur,
                                                               stage);
  binbase_kernel<<<1, 64, 0, stream>>>(bincur, binbase, rowptr);
  bin_csr_kernel<<<dim3(NBINS, NB), 256, 0, stream>>>(stage, bincur, binbase,
                                                      rowptr, dis, inv, csr);

  // ---- layer 1: x @ W1 -> 16, gather(+bias+tanh) ----
  mm1_kernel<<<4096, 256, 0, stream>>>(x, W1, bufA);
  gather_kernel<16, true, true><<<dim3(NNODES / 16, NB), 256, 0, stream>>>(
      rowptr, csr, dis, inv, bufA, b1, bufB);

  // ---- layer 2: aggregate h1 (16) then W2+b2+tanh ----
  gather_kernel<16, false, false><<<dim3(NNODES / 16, NB), 256, 0, stream>>>(
      rowptr, csr, dis, inv, bufB, b2, bufA);
  mmfuse_kernel<16, true><<<(int)(BN * 16 / 256), 256, 0, stream>>>(bufA, W2,
                                                                    b2, bufB);

  // ---- layer 3: aggregate h2 (16) then W3+b3 ----
  gather_kernel<16, false, false><<<dim3(NNODES / 16, NB), 256, 0, stream>>>(
      rowptr, csr, dis, inv, bufB, b3, bufA);
  mmfuse_kernel<32, false><<<(int)(BN * 32 / 256), 256, 0, stream>>>(bufA, W3,
                                                                     b3, bufB);

  // ---- gather + MLP head ----
  fc_kernel<<<NB, 256, 0, stream>>>(bufB, pos, fcW1, fcb1, fcW2, fcb2, fcW3,
                                    fcb3, out);
}